// Round 1
// baseline (1596.257 us; speedup 1.0000x reference)
//
#include <hip/hip_runtime.h>
#include <hip/hip_bf16.h>
#include <cstdint>
#include <cstddef>

// ---------------------------------------------------------------------------
// Parser tree expansion — round 5: 256x256 8-wave double-buffered pipelined
// GEMM (T2+T3+T5 stack) for the large levels (d>=7 branch/resid, final gi).
// B=64, S=32, H=1024, R=256, DEPTH=9. Output [64, 512, 1025] fp32.
// ---------------------------------------------------------------------------

#define SELU_L 1.0507009873554805f
#define SELU_A 1.6732632423543772f

__device__ __forceinline__ float selu_f(float x) {
    return x > 0.f ? SELU_L * x : (SELU_L * SELU_A) * (__expf(x) - 1.f);
}
__device__ __forceinline__ float sigmoid_f(float x) {
    return 1.f / (1.f + __expf(-x));
}

typedef __attribute__((ext_vector_type(8))) short s16x8;
typedef __attribute__((ext_vector_type(4))) float f32x4;

__device__ __forceinline__ void gld16(const void* g, void* l) {
    __builtin_amdgcn_global_load_lds(
        (const __attribute__((address_space(1))) uint32_t*)g,
        (__attribute__((address_space(3))) uint32_t*)l, 16, 0, 0);
}

enum { AM_PLAIN = 0, AM_CONCAT = 2 };
enum { EP_NONE = 0, EP_SELU32 = 1, EP_BRANCH = 2, EP_RESID = 3 };

// ===========================================================================
// Legacy 128x128 path (small/medium levels): BK=64, 4 waves, serial staging.
// ===========================================================================
template <int AMODE, int EPI>
__device__ __forceinline__ void gemm_body(
    int bm, int bn, int M, int K,
    const __hip_bfloat16* __restrict__ A, int lda,
    const __hip_bfloat16* __restrict__ A2,
    const __hip_bfloat16* __restrict__ W,
    const float* __restrict__ bias,
    void* __restrict__ Cv, int ldc,
    const __hip_bfloat16* __restrict__ P,
    float* __restrict__ C32, int ldc32,
    short* As, short* Bs)
{
    const int tid  = threadIdx.x;
    const int wave = tid >> 6;
    const int lane = tid & 63;

    const short* gA[4]; const short* gA2p[4]; const short* gB[4];
    short* dA[4]; short* dB[4];
#pragma unroll
    for (int r = 0; r < 4; ++r) {
        const int s   = r * 256 + wave * 64 + lane;
        const int row = s >> 3;
        const int pc  = s & 7;
        const int j   = (pc - (row >> 1)) & 7;
        const int ga  = min(bm + row, M - 1);
        if (AMODE == AM_CONCAT) {
            gA[r]   = (const short*)A  + (size_t)ga * 1024 + j * 8;
            gA2p[r] = (const short*)A2 + (size_t)ga * 256  + j * 8;
        } else {
            gA[r]   = (const short*)A + (size_t)ga * lda + j * 8;
            gA2p[r] = nullptr;
        }
        gB[r] = (const short*)W + (size_t)(bn + row) * K + j * 8;
        dA[r] = &As[(size_t)(r * 256 + wave * 64) * 8];
        dB[r] = &Bs[(size_t)(r * 256 + wave * 64) * 8];
    }

    const int wm = (wave >> 1) * 64, wn = (wave & 1) * 64;
    const int l16 = lane & 15, q4 = lane >> 4;
    int aoff[4], boff[4];
#pragma unroll
    for (int i = 0; i < 4; ++i) {
        int ra = wm + i * 16 + l16;
        aoff[i] = ra * 64 + (((q4 + (ra >> 1)) & 7) << 3);
        int rb = wn + i * 16 + l16;
        boff[i] = rb * 64 + (((q4 + (rb >> 1)) & 7) << 3);
    }

    f32x4 acc[4][4] = {};

    for (int k0 = 0; k0 < K; k0 += 64) {
#pragma unroll
        for (int r = 0; r < 4; ++r) {
            const short* ap;
            if (AMODE == AM_CONCAT)
                ap = (k0 < 1024) ? gA[r] + k0 : gA2p[r] + (k0 - 1024);
            else
                ap = gA[r] + k0;
            gld16(ap, dA[r]);
            gld16(gB[r] + k0, dB[r]);
        }
        __syncthreads();

#pragma unroll
        for (int h = 0; h < 2; ++h) {
            const int hx = h << 5;
            s16x8 af[4], bf[4];
#pragma unroll
            for (int i = 0; i < 4; ++i) af[i] = *(const s16x8*)&As[aoff[i] ^ hx];
#pragma unroll
            for (int i = 0; i < 4; ++i) bf[i] = *(const s16x8*)&Bs[boff[i] ^ hx];
#pragma unroll
            for (int mi = 0; mi < 4; ++mi)
#pragma unroll
                for (int ni = 0; ni < 4; ++ni)
                    acc[mi][ni] = __builtin_amdgcn_mfma_f32_16x16x32_bf16(
                        af[mi], bf[ni], acc[mi][ni], 0, 0, 0);
        }
        __syncthreads();
    }

    const int crow0 = bm + wm + q4 * 4;
    const int ccol0 = bn + wn + l16;
#pragma unroll
    for (int mi = 0; mi < 4; ++mi) {
#pragma unroll
        for (int r = 0; r < 4; ++r) {
            const int row = crow0 + mi * 16 + r;
            if (row >= M) continue;
#pragma unroll
            for (int ni = 0; ni < 4; ++ni) {
                const int col = ccol0 + ni * 16;
                float v = acc[mi][ni][r] + bias[col];
                if (EPI == EP_NONE) {
                    ((float*)Cv)[(size_t)row * ldc + col] = v;
                } else if (EPI == EP_SELU32) {
                    ((float*)Cv)[(size_t)row * ldc + col] = selu_f(v);
                } else if (EPI == EP_BRANCH) {
                    const int c = col >> 10, jj = col & 1023;
                    ((__hip_bfloat16*)Cv)[(size_t)(2 * row + c) * 1024 + jj] =
                        __float2bfloat16(selu_f(v));
                } else { // EP_RESID
                    const float pv = __bfloat162float(P[(size_t)(row >> 1) * 1024 + col]);
                    const float o = pv - selu_f(v);
                    ((__hip_bfloat16*)Cv)[(size_t)row * 1024 + col] = __float2bfloat16(o);
                    if (C32) C32[(size_t)row * ldc32 + col] = o;
                }
            }
        }
    }
}

template <int AMODE, int EPI>
__global__ __launch_bounds__(256) void mgemm(
    int M, int N, int K,
    const __hip_bfloat16* __restrict__ A, int lda,
    const __hip_bfloat16* __restrict__ A2,
    const __hip_bfloat16* __restrict__ W,
    const float* __restrict__ bias,
    void* __restrict__ Cv, int ldc,
    const __hip_bfloat16* __restrict__ P,
    float* __restrict__ C32, int ldc32)
{
    __shared__ short As[8192];
    __shared__ short Bs[8192];
    int bxi = blockIdx.x, byi = blockIdx.y;
    {
        const int ncol = gridDim.x, nrow = gridDim.y;
        if ((nrow & 7) == 0) {
            const int lin = byi * ncol + bxi;
            const int xcd = lin & 7;
            const int t = lin >> 3;
            const int rows_per = nrow >> 3;
            bxi = t % ncol;
            byi = xcd * rows_per + t / ncol;
        }
    }
    gemm_body<AMODE, EPI>(byi * 128, bxi * 128, M, K, A, lda, A2, W, bias,
                          Cv, ldc, P, C32, ldc32, As, Bs);
}

struct GPair {
    int M0, K0; const __hip_bfloat16* A0; int lda0;
    const __hip_bfloat16* W0; const float* b0; float* C0; int ldc0;
    int M1, K1; const __hip_bfloat16* A1; int lda1;
    const __hip_bfloat16* W1; const float* b1; float* C1; int ldc1;
};
__global__ __launch_bounds__(256) void mgemm_pair(GPair g)
{
    __shared__ short As[8192];
    __shared__ short Bs[8192];
    int bxi = blockIdx.x, byi = blockIdx.y;
    if (blockIdx.z == 0) {
        const int ncol = gridDim.x, nrow = gridDim.y;
        if ((nrow & 7) == 0) {
            const int lin = byi * ncol + bxi;
            const int xcd = lin & 7;
            const int t = lin >> 3;
            const int rows_per = nrow >> 3;
            bxi = t % ncol;
            byi = xcd * rows_per + t / ncol;
        }
        gemm_body<AM_PLAIN, EP_NONE>(byi * 128, bxi * 128, g.M0, g.K0,
                                     g.A0, g.lda0, nullptr, g.W0, g.b0,
                                     g.C0, g.ldc0, nullptr, nullptr, 0, As, Bs);
    } else {
        if (byi * 128 >= g.M1) return;
        gemm_body<AM_PLAIN, EP_NONE>(byi * 128, bxi * 128, g.M1, g.K1,
                                     g.A1, g.lda1, nullptr, g.W1, g.b1,
                                     g.C1, g.ldc1, nullptr, nullptr, 0, As, Bs);
    }
}

// ===========================================================================
// New 256x256 path: 8 waves (2Mx4N), BK=32, LDS double-buffered (64 KiB),
// distance-1 prefetch issued at phase-A start, single vmcnt(0) drain at tile
// end (~2 MFMA phases = ~1000 cy of cover), raw barriers + setprio around
// each 16-MFMA cluster. LDS reads/FLOP 1.5x lower than the 128^2 path.
// ===========================================================================
template <int AMODE, int EPI>
__device__ __forceinline__ void gemm256_body(
    int bm, int bn, int M, int K,
    const __hip_bfloat16* __restrict__ A, int lda,
    const __hip_bfloat16* __restrict__ A2,
    const __hip_bfloat16* __restrict__ W,
    const float* __restrict__ bias,
    void* __restrict__ Cv, int ldc,
    const __hip_bfloat16* __restrict__ P,
    float* __restrict__ C32, int ldc32,
    short* As, short* Bs)   // 16384 shorts each: [2 buf][256 rows][32 k]
{
    const int tid  = threadIdx.x;
    const int wave = tid >> 6;
    const int lane = tid & 63;
    const int wm = (wave >> 2) * 128;      // 2 row-waves
    const int wn = (wave & 3) * 64;        // 4 col-waves
    const int l16 = lane & 15, q4 = lane >> 4;

    // ---- staging maps: per tensor 2 block-wide gld16 per 32-K tile ----
    // slot s = r*512 + tid; row = s>>2; phys chunk pc = s&3; logical j = (pc - row>>1)&3
    const short* gA[2]; const short* gA2p[2]; const short* gB[2];
    int dOf[2];
#pragma unroll
    for (int r = 0; r < 2; ++r) {
        const int s   = r * 512 + tid;
        const int row = s >> 2;
        const int pc  = s & 3;
        const int j   = (pc - (row >> 1)) & 3;
        const int ga  = min(bm + row, M - 1);
        if (AMODE == AM_CONCAT) {
            gA[r]   = (const short*)A  + (size_t)ga * 1024 + j * 8;
            gA2p[r] = (const short*)A2 + (size_t)ga * 256  + j * 8;
        } else {
            gA[r]   = (const short*)A + (size_t)ga * lda + j * 8;
            gA2p[r] = nullptr;
        }
        gB[r]  = (const short*)W + (size_t)(bn + row) * K + j * 8;
        dOf[r] = (r * 512 + wave * 64) * 8;   // wave-uniform LDS base (shorts)
    }

    // ---- fragment read offsets (buffer 0; add 8192 for buffer 1) ----
    int aof[2][4], bof[4];
#pragma unroll
    for (int mh = 0; mh < 2; ++mh)
#pragma unroll
        for (int i = 0; i < 4; ++i) {
            const int ra = wm + mh * 64 + i * 16 + l16;
            aof[mh][i] = ra * 32 + (((q4 + (ra >> 1)) & 3) << 3);
        }
#pragma unroll
    for (int n = 0; n < 4; ++n) {
        const int rb = wn + n * 16 + l16;
        bof[n] = rb * 32 + (((q4 + (rb >> 1)) & 3) << 3);
    }

    f32x4 acc[8][4] = {};
    const int NT = K >> 5;

    // ---- prologue: stage tile 0 into buffer 0, drain, sync ----
#pragma unroll
    for (int r = 0; r < 2; ++r) gld16(gA[r], &As[dOf[r]]);
#pragma unroll
    for (int r = 0; r < 2; ++r) gld16(gB[r], &Bs[dOf[r]]);
    asm volatile("s_waitcnt vmcnt(0)" ::: "memory");
    __builtin_amdgcn_s_barrier();

    for (int t = 0; t < NT; ++t) {
        const int cur = (t & 1) << 13;       // 0 / 8192
        const int nxt = 8192 - cur;
        const int k1  = (t + 1) << 5;

        // ======== phase A: stage(t+1) + read (mh=0 A-frags, all B) + 16 MFMA
        if (t + 1 < NT) {
#pragma unroll
            for (int r = 0; r < 2; ++r) {
                const short* ap;
                if (AMODE == AM_CONCAT)
                    ap = (k1 < 1024) ? gA[r] + k1 : gA2p[r] + (k1 - 1024);
                else
                    ap = gA[r] + k1;
                gld16(ap, &As[nxt + dOf[r]]);
            }
#pragma unroll
            for (int r = 0; r < 2; ++r) gld16(gB[r] + k1, &Bs[nxt + dOf[r]]);
        }
        s16x8 af[4], bf[4];
#pragma unroll
        for (int i = 0; i < 4; ++i) af[i] = *(const s16x8*)&As[cur + aof[0][i]];
#pragma unroll
        for (int n = 0; n < 4; ++n) bf[n] = *(const s16x8*)&Bs[cur + bof[n]];
        __builtin_amdgcn_s_barrier();
        __builtin_amdgcn_s_setprio(1);
#pragma unroll
        for (int mi = 0; mi < 4; ++mi)
#pragma unroll
            for (int n = 0; n < 4; ++n)
                acc[mi][n] = __builtin_amdgcn_mfma_f32_16x16x32_bf16(
                    af[mi], bf[n], acc[mi][n], 0, 0, 0);
        __builtin_amdgcn_s_setprio(0);
        __builtin_amdgcn_s_barrier();

        // ======== phase B: read mh=1 A-frags (reuse B) + 16 MFMA
#pragma unroll
        for (int i = 0; i < 4; ++i) af[i] = *(const s16x8*)&As[cur + aof[1][i]];
        __builtin_amdgcn_s_barrier();
        __builtin_amdgcn_s_setprio(1);
#pragma unroll
        for (int mi = 0; mi < 4; ++mi)
#pragma unroll
            for (int n = 0; n < 4; ++n)
                acc[4 + mi][n] = __builtin_amdgcn_mfma_f32_16x16x32_bf16(
                    af[mi], bf[n], acc[4 + mi][n], 0, 0, 0);
        __builtin_amdgcn_s_setprio(0);
        // drain staging of t+1 (issued ~2 MFMA phases ago -> latency hidden)
        asm volatile("s_waitcnt vmcnt(0)" ::: "memory");
        __builtin_amdgcn_s_barrier();
    }

    // ---- epilogue ----
    const int crow0 = bm + wm + q4 * 4;
    const int ccol0 = bn + wn + l16;
#pragma unroll
    for (int m8 = 0; m8 < 8; ++m8) {
#pragma unroll
        for (int r = 0; r < 4; ++r) {
            const int row = crow0 + m8 * 16 + r;
            if (row >= M) continue;
#pragma unroll
            for (int n4 = 0; n4 < 4; ++n4) {
                const int col = ccol0 + n4 * 16;
                float v = acc[m8][n4][r] + bias[col];
                if (EPI == EP_NONE) {
                    ((float*)Cv)[(size_t)row * ldc + col] = v;
                } else if (EPI == EP_SELU32) {
                    ((float*)Cv)[(size_t)row * ldc + col] = selu_f(v);
                } else if (EPI == EP_BRANCH) {
                    const int c = col >> 10, jj = col & 1023;
                    ((__hip_bfloat16*)Cv)[(size_t)(2 * row + c) * 1024 + jj] =
                        __float2bfloat16(selu_f(v));
                } else { // EP_RESID
                    const float pv = __bfloat162float(P[(size_t)(row >> 1) * 1024 + col]);
                    const float o = pv - selu_f(v);
                    ((__hip_bfloat16*)Cv)[(size_t)row * 1024 + col] = __float2bfloat16(o);
                    if (C32) C32[(size_t)row * ldc32 + col] = o;
                }
            }
        }
    }
}

template <int AMODE, int EPI>
__global__ __launch_bounds__(512) void mgemm256(
    int M, int N, int K,
    const __hip_bfloat16* __restrict__ A, int lda,
    const __hip_bfloat16* __restrict__ A2,
    const __hip_bfloat16* __restrict__ W,
    const float* __restrict__ bias,
    void* __restrict__ Cv, int ldc,
    const __hip_bfloat16* __restrict__ P,
    float* __restrict__ C32, int ldc32)
{
    __shared__ short As[16384];
    __shared__ short Bs[16384];
    int bxi = blockIdx.x, byi = blockIdx.y;
    {
        const int ncol = gridDim.x, nrow = gridDim.y;
        if ((nrow & 7) == 0) {
            const int lin = byi * ncol + bxi;
            const int xcd = lin & 7;
            const int t = lin >> 3;
            const int rows_per = nrow >> 3;
            bxi = t % ncol;
            byi = xcd * rows_per + t / ncol;
        }
    }
    gemm256_body<AMODE, EPI>(byi * 256, bxi * 256, M, K, A, lda, A2, W, bias,
                             Cv, ldc, P, C32, ldc32, As, Bs);
}

// ---- elementwise helpers ----
__global__ void cvt4_k(const float* __restrict__ s0, __hip_bfloat16* __restrict__ d0, int n0,
                       const float* __restrict__ s1, __hip_bfloat16* __restrict__ d1, int n1,
                       const float* __restrict__ s2, __hip_bfloat16* __restrict__ d2, int n2,
                       const float* __restrict__ s3, __hip_bfloat16* __restrict__ d3, int n3)
{
    int i = blockIdx.x * 256 + threadIdx.x;
    if (i < n0) { d0[i] = __float2bfloat16(s0[i]); return; }
    i -= n0;
    if (i < n1) { d1[i] = __float2bfloat16(s1[i]); return; }
    i -= n1;
    if (i < n2) { d2[i] = __float2bfloat16(s2[i]); return; }
    i -= n2;
    if (i < n3) { d3[i] = __float2bfloat16(s3[i]); }
}

__global__ void selu_cvt_k(const float* __restrict__ in, __hip_bfloat16* __restrict__ out, int n)
{
    int i = blockIdx.x * 256 + threadIdx.x;
    if (i < n) out[i] = __float2bfloat16(selu_f(in[i]));
}

__global__ void mean_kernel(const float* __restrict__ T, __hip_bfloat16* __restrict__ xc)
{
    const int idx = blockIdx.x * 256 + threadIdx.x; // 64*1024
    const int b = idx >> 10, h = idx & 1023;
    const float* p = T + (size_t)b * 32 * 1024 + h;
    float s = 0.f;
#pragma unroll
    for (int si = 0; si < 32; ++si) s += p[si * 1024];
    xc[idx] = __float2bfloat16(s * (1.f / 32.f));
}

__global__ __launch_bounds__(256) void gateshb_kernel(
    const float* __restrict__ gi,
    const float* __restrict__ gh,
    const float* __restrict__ b_hh,
    const __hip_bfloat16* __restrict__ hold,
    __hip_bfloat16* __restrict__ hnew,
    const __hip_bfloat16* __restrict__ xc,
    const float* __restrict__ W_hb,
    const float* __restrict__ b_hb,
    const float* __restrict__ depth_old,
    float* __restrict__ depth_out, int dstride,
    int first)
{
    const int m = blockIdx.x;
    const int j = threadIdx.x;
    __shared__ float red[4];

    const float* gim = gi + (size_t)m * 768;
    const float ir = gim[j], iz = gim[256 + j], in_ = gim[512 + j];
    float hr, hz, hn, h0;
    if (first) {
        hr = b_hh[j]; hz = b_hh[256 + j]; hn = b_hh[512 + j]; h0 = 0.f;
    } else {
        const float* ghm = gh + (size_t)(m >> 1) * 768;
        hr = ghm[j]; hz = ghm[256 + j]; hn = ghm[512 + j];
        h0 = __bfloat162float(hold[(size_t)(m >> 1) * 256 + j]);
    }
    const float r = sigmoid_f(ir + hr);
    const float z = sigmoid_f(iz + hz);
    const float n = tanhf(in_ + r * hn);
    const float hv = (1.f - z) * n + z * h0;
    hnew[(size_t)m * 256 + j] = __float2bfloat16(hv);

    const __hip_bfloat16* xr = xc + (size_t)m * 1024;
    float s = hv * W_hb[1024 + j];
#pragma unroll
    for (int kk = 0; kk < 4; ++kk) {
        const int k = j + kk * 256;
        s += __bfloat162float(xr[k]) * W_hb[k];
    }
#pragma unroll
    for (int off = 32; off; off >>= 1) s += __shfl_down(s, off);
    if ((j & 63) == 0) red[j >> 6] = s;
    __syncthreads();
    if (j == 0) {
        const float tot = red[0] + red[1] + red[2] + red[3];
        const float hb = sigmoid_f(tot + b_hb[0]);
        const float d0 = first ? 0.f : depth_old[m >> 1];
        depth_out[(size_t)m * dstride] = d0 + hb;
    }
}

extern "C" void kernel_launch(void* const* d_in, const int* in_sizes, int n_in,
                              void* d_out, int out_size, void* d_ws, size_t ws_size,
                              hipStream_t stream)
{
    const float* x        = (const float*)d_in[0];
    const float* W_hidden = (const float*)d_in[1];
    const float* b_hidden = (const float*)d_in[2];
    const float* W_hb     = (const float*)d_in[3];
    const float* b_hb     = (const float*)d_in[4];
    const float* W_branch = (const float*)d_in[5];
    const float* b_branch = (const float*)d_in[6];
    const float* W_ih     = (const float*)d_in[7];
    const float* W_hh     = (const float*)d_in[8];
    const float* b_ih     = (const float*)d_in[9];
    const float* b_hh     = (const float*)d_in[10];

    char* ws = (char*)d_ws;
    size_t off = 0;
    auto alloc = [&](size_t bytes) {
        void* p = ws + off;
        off += (bytes + 255) & ~(size_t)255;
        return p;
    };
    __hip_bfloat16* Whb  = (__hip_bfloat16*)alloc(1024 * 1024 * 2);
    __hip_bfloat16* Wbb  = (__hip_bfloat16*)alloc(2048 * 1280 * 2);
    __hip_bfloat16* Wib  = (__hip_bfloat16*)alloc(768 * 1024 * 2);
    __hip_bfloat16* Whh  = (__hip_bfloat16*)alloc(768 * 256 * 2);
    __hip_bfloat16* Xs   = (__hip_bfloat16*)alloc((size_t)2048 * 1024 * 2);
    float*          GI   = (float*)alloc((size_t)32768 * 768 * 4);
    __hip_bfloat16* U    = (__hip_bfloat16*)alloc((size_t)32768 * 1024 * 2);
    __hip_bfloat16* XC0  = (__hip_bfloat16*)alloc((size_t)32768 * 1024 * 2);
    __hip_bfloat16* XC1  = (__hip_bfloat16*)alloc((size_t)32768 * 1024 * 2);
    __hip_bfloat16* HC0  = (__hip_bfloat16*)alloc((size_t)32768 * 256 * 2);
    __hip_bfloat16* HC1  = (__hip_bfloat16*)alloc((size_t)32768 * 256 * 2);
    float*          D0   = (float*)alloc(32768 * 4);
    float*          D1   = (float*)alloc(32768 * 4);
    float*          GH   = (float*)U;

    float* out = (float*)d_out; // [32768, 1025]

    {
        const int n0 = 1024 * 1024, n1 = 2048 * 1280, n2 = 768 * 1024, n3 = 768 * 256;
        cvt4_k<<<(n0 + n1 + n2 + n3 + 255) / 256, 256, 0, stream>>>(
            W_hidden, Whb, n0, W_branch, Wbb, n1, W_ih, Wib, n2, W_hh, Whh, n3);
    }
    selu_cvt_k<<<(2048 * 1024 + 255) / 256, 256, 0, stream>>>(x, Xs, 2048 * 1024);

    mgemm<AM_PLAIN, EP_SELU32><<<dim3(1024 / 128, 2048 / 128), 256, 0, stream>>>(
        2048, 1024, 1024, Xs, 1024, nullptr, Whb, b_hidden, GI, 1024, nullptr, nullptr, 0);
    mean_kernel<<<(64 * 1024) / 256, 256, 0, stream>>>(GI, XC0);

    __hip_bfloat16* xc_cur = XC0; __hip_bfloat16* xc_next = XC1;
    __hip_bfloat16* hc_prev = nullptr; __hip_bfloat16* hc_new = HC0;
    float* d_prev = nullptr; float* d_next = D0;

    for (int d = 0; d < 9; ++d) {
        const int M = 64 << d; // 64 .. 16384
        GPair g;
        g.M0 = M;     g.K0 = 1024; g.A0 = xc_cur;  g.lda0 = 1024;
        g.W0 = Wib;   g.b0 = b_ih; g.C0 = GI;      g.ldc0 = 768;
        g.M1 = M / 2; g.K1 = 256;  g.A1 = hc_prev; g.lda1 = 256;
        g.W1 = Whh;   g.b1 = b_hh; g.C1 = GH;      g.ldc1 = 768;
        mgemm_pair<<<dim3(768 / 128, (M + 127) / 128, d > 0 ? 2 : 1), 256, 0, stream>>>(g);

        gateshb_kernel<<<M, 256, 0, stream>>>(
            GI, (const float*)GH, b_hh, hc_prev, hc_new,
            xc_cur, W_hb, b_hb, d_prev, d_next, 1, d == 0 ? 1 : 0);

        if (d >= 7) {
            // large levels: 256^2 pipelined path
            mgemm256<AM_CONCAT, EP_BRANCH><<<dim3(2048 / 256, M / 256), 512, 0, stream>>>(
                M, 2048, 1280, xc_cur, 1024, hc_new, Wbb, b_branch, U, 1024,
                nullptr, nullptr, 0);
            mgemm256<AM_PLAIN, EP_RESID><<<dim3(1024 / 256, (2 * M) / 256), 512, 0, stream>>>(
                2 * M, 1024, 1024, U, 1024, nullptr, Whb, b_hidden, xc_next, 1024,
                xc_cur, d == 8 ? out : nullptr, 1025);
        } else {
            mgemm<AM_CONCAT, EP_BRANCH><<<dim3(2048 / 128, (M + 127) / 128), 256, 0, stream>>>(
                M, 2048, 1280, xc_cur, 1024, hc_new, Wbb, b_branch, U, 1024,
                nullptr, nullptr, 0);
            mgemm<AM_PLAIN, EP_RESID><<<dim3(1024 / 128, (2 * M) / 128), 256, 0, stream>>>(
                2 * M, 1024, 1024, U, 1024, nullptr, Whb, b_hidden, xc_next, 1024,
                xc_cur, d == 8 ? out : nullptr, 1025);
        }

        __hip_bfloat16* t = xc_cur; xc_cur = xc_next; xc_next = t;
        hc_prev = hc_new; hc_new = (hc_new == HC0) ? HC1 : HC0;
        d_prev = d_next;  d_next = (d_next == D0) ? D1 : D0;
    }

    // ---- final GRU + leaf depth, M = 32768 ----
    {
        const int M = 32768;
        // gi on the 256^2 path (384 blocks), gh on the legacy path
        mgemm256<AM_PLAIN, EP_NONE><<<dim3(768 / 256, M / 256), 512, 0, stream>>>(
            M, 768, 1024, xc_cur, 1024, nullptr, Wib, b_ih, GI, 768,
            nullptr, nullptr, 0);
        mgemm<AM_PLAIN, EP_NONE><<<dim3(768 / 128, (M / 2) / 128), 256, 0, stream>>>(
            M / 2, 768, 256, hc_prev, 256, nullptr, Whh, b_hh, (void*)GH, 768,
            nullptr, nullptr, 0);
        gateshb_kernel<<<M, 256, 0, stream>>>(
            GI, (const float*)GH, b_hh, hc_prev, hc_new,
            xc_cur, W_hb, b_hb, d_prev, out + 1024, 1025, 0);
    }
}

// Round 3
// 1463.584 us; speedup vs baseline: 1.0906x; 1.0906x over previous
//
#include <hip/hip_runtime.h>
#include <hip/hip_bf16.h>
#include <cstdint>
#include <cstddef>

// ---------------------------------------------------------------------------
// Parser tree expansion — round 7: fixed 4-slot ring. stage(t+3) is issued
// AFTER the per-tile barrier (write-after-read hazard on slot (t-1)&3 is then
// provably ordered: barrier arrival requires prior tile's MFMAs -> lgkmcnt
// drain -> ds_reads complete). vmcnt counts adjusted: 8/8/4/0.
// Routed to grids >= 256 blocks (branch/resid d>=7, final gi).
// B=64, S=32, H=1024, R=256, DEPTH=9. Output [64, 512, 1025] fp32.
// ---------------------------------------------------------------------------

#define SELU_L 1.0507009873554805f
#define SELU_A 1.6732632423543772f

__device__ __forceinline__ float selu_f(float x) {
    return x > 0.f ? SELU_L * x : (SELU_L * SELU_A) * (__expf(x) - 1.f);
}
__device__ __forceinline__ float sigmoid_f(float x) {
    return 1.f / (1.f + __expf(-x));
}

typedef __attribute__((ext_vector_type(8))) short s16x8;
typedef __attribute__((ext_vector_type(4))) float f32x4;

__device__ __forceinline__ void gld16(const void* g, void* l) {
    __builtin_amdgcn_global_load_lds(
        (const __attribute__((address_space(1))) uint32_t*)g,
        (__attribute__((address_space(3))) uint32_t*)l, 16, 0, 0);
}

enum { AM_PLAIN = 0, AM_CONCAT = 2 };
enum { EP_NONE = 0, EP_SELU32 = 1, EP_BRANCH = 2, EP_RESID = 3 };

// ===========================================================================
// Legacy 128x128 path (small/medium levels): BK=64, 4 waves, serial staging.
// ===========================================================================
template <int AMODE, int EPI>
__device__ __forceinline__ void gemm_body(
    int bm, int bn, int M, int K,
    const __hip_bfloat16* __restrict__ A, int lda,
    const __hip_bfloat16* __restrict__ A2,
    const __hip_bfloat16* __restrict__ W,
    const float* __restrict__ bias,
    void* __restrict__ Cv, int ldc,
    const __hip_bfloat16* __restrict__ P,
    float* __restrict__ C32, int ldc32,
    short* As, short* Bs)
{
    const int tid  = threadIdx.x;
    const int wave = tid >> 6;
    const int lane = tid & 63;

    const short* gA[4]; const short* gA2p[4]; const short* gB[4];
    short* dA[4]; short* dB[4];
#pragma unroll
    for (int r = 0; r < 4; ++r) {
        const int s   = r * 256 + wave * 64 + lane;
        const int row = s >> 3;
        const int pc  = s & 7;
        const int j   = (pc - (row >> 1)) & 7;
        const int ga  = min(bm + row, M - 1);
        if (AMODE == AM_CONCAT) {
            gA[r]   = (const short*)A  + (size_t)ga * 1024 + j * 8;
            gA2p[r] = (const short*)A2 + (size_t)ga * 256  + j * 8;
        } else {
            gA[r]   = (const short*)A + (size_t)ga * lda + j * 8;
            gA2p[r] = nullptr;
        }
        gB[r] = (const short*)W + (size_t)(bn + row) * K + j * 8;
        dA[r] = &As[(size_t)(r * 256 + wave * 64) * 8];
        dB[r] = &Bs[(size_t)(r * 256 + wave * 64) * 8];
    }

    const int wm = (wave >> 1) * 64, wn = (wave & 1) * 64;
    const int l16 = lane & 15, q4 = lane >> 4;
    int aoff[4], boff[4];
#pragma unroll
    for (int i = 0; i < 4; ++i) {
        int ra = wm + i * 16 + l16;
        aoff[i] = ra * 64 + (((q4 + (ra >> 1)) & 7) << 3);
        int rb = wn + i * 16 + l16;
        boff[i] = rb * 64 + (((q4 + (rb >> 1)) & 7) << 3);
    }

    f32x4 acc[4][4] = {};

    for (int k0 = 0; k0 < K; k0 += 64) {
#pragma unroll
        for (int r = 0; r < 4; ++r) {
            const short* ap;
            if (AMODE == AM_CONCAT)
                ap = (k0 < 1024) ? gA[r] + k0 : gA2p[r] + (k0 - 1024);
            else
                ap = gA[r] + k0;
            gld16(ap, dA[r]);
            gld16(gB[r] + k0, dB[r]);
        }
        __syncthreads();

#pragma unroll
        for (int h = 0; h < 2; ++h) {
            const int hx = h << 5;
            s16x8 af[4], bf[4];
#pragma unroll
            for (int i = 0; i < 4; ++i) af[i] = *(const s16x8*)&As[aoff[i] ^ hx];
#pragma unroll
            for (int i = 0; i < 4; ++i) bf[i] = *(const s16x8*)&Bs[boff[i] ^ hx];
#pragma unroll
            for (int mi = 0; mi < 4; ++mi)
#pragma unroll
                for (int ni = 0; ni < 4; ++ni)
                    acc[mi][ni] = __builtin_amdgcn_mfma_f32_16x16x32_bf16(
                        af[mi], bf[ni], acc[mi][ni], 0, 0, 0);
        }
        __syncthreads();
    }

    const int crow0 = bm + wm + q4 * 4;
    const int ccol0 = bn + wn + l16;
#pragma unroll
    for (int mi = 0; mi < 4; ++mi) {
#pragma unroll
        for (int r = 0; r < 4; ++r) {
            const int row = crow0 + mi * 16 + r;
            if (row >= M) continue;
#pragma unroll
            for (int ni = 0; ni < 4; ++ni) {
                const int col = ccol0 + ni * 16;
                float v = acc[mi][ni][r] + bias[col];
                if (EPI == EP_NONE) {
                    ((float*)Cv)[(size_t)row * ldc + col] = v;
                } else if (EPI == EP_SELU32) {
                    ((float*)Cv)[(size_t)row * ldc + col] = selu_f(v);
                } else if (EPI == EP_BRANCH) {
                    const int c = col >> 10, jj = col & 1023;
                    ((__hip_bfloat16*)Cv)[(size_t)(2 * row + c) * 1024 + jj] =
                        __float2bfloat16(selu_f(v));
                } else { // EP_RESID
                    const float pv = __bfloat162float(P[(size_t)(row >> 1) * 1024 + col]);
                    const float o = pv - selu_f(v);
                    ((__hip_bfloat16*)Cv)[(size_t)row * 1024 + col] = __float2bfloat16(o);
                    if (C32) C32[(size_t)row * ldc32 + col] = o;
                }
            }
        }
    }
}

template <int AMODE, int EPI>
__global__ __launch_bounds__(256) void mgemm(
    int M, int N, int K,
    const __hip_bfloat16* __restrict__ A, int lda,
    const __hip_bfloat16* __restrict__ A2,
    const __hip_bfloat16* __restrict__ W,
    const float* __restrict__ bias,
    void* __restrict__ Cv, int ldc,
    const __hip_bfloat16* __restrict__ P,
    float* __restrict__ C32, int ldc32)
{
    __shared__ short As[8192];
    __shared__ short Bs[8192];
    int bxi = blockIdx.x, byi = blockIdx.y;
    {
        const int ncol = gridDim.x, nrow = gridDim.y;
        if ((nrow & 7) == 0) {
            const int lin = byi * ncol + bxi;
            const int xcd = lin & 7;
            const int t = lin >> 3;
            const int rows_per = nrow >> 3;
            bxi = t % ncol;
            byi = xcd * rows_per + t / ncol;
        }
    }
    gemm_body<AMODE, EPI>(byi * 128, bxi * 128, M, K, A, lda, A2, W, bias,
                          Cv, ldc, P, C32, ldc32, As, Bs);
}

struct GPair {
    int M0, K0; const __hip_bfloat16* A0; int lda0;
    const __hip_bfloat16* W0; const float* b0; float* C0; int ldc0;
    int M1, K1; const __hip_bfloat16* A1; int lda1;
    const __hip_bfloat16* W1; const float* b1; float* C1; int ldc1;
};
__global__ __launch_bounds__(256) void mgemm_pair(GPair g)
{
    __shared__ short As[8192];
    __shared__ short Bs[8192];
    int bxi = blockIdx.x, byi = blockIdx.y;
    if (blockIdx.z == 0) {
        const int ncol = gridDim.x, nrow = gridDim.y;
        if ((nrow & 7) == 0) {
            const int lin = byi * ncol + bxi;
            const int xcd = lin & 7;
            const int t = lin >> 3;
            const int rows_per = nrow >> 3;
            bxi = t % ncol;
            byi = xcd * rows_per + t / ncol;
        }
        gemm_body<AM_PLAIN, EP_NONE>(byi * 128, bxi * 128, g.M0, g.K0,
                                     g.A0, g.lda0, nullptr, g.W0, g.b0,
                                     g.C0, g.ldc0, nullptr, nullptr, 0, As, Bs);
    } else {
        if (byi * 128 >= g.M1) return;
        gemm_body<AM_PLAIN, EP_NONE>(byi * 128, bxi * 128, g.M1, g.K1,
                                     g.A1, g.lda1, nullptr, g.W1, g.b1,
                                     g.C1, g.ldc1, nullptr, nullptr, 0, As, Bs);
    }
}

// ===========================================================================
// 256x256 pipelined path, v3 (race-fixed): 8 waves (2Mx4N), per-wave 128x64.
// BK=32, 4-slot LDS ring (128 KiB), prefetch distance 3.
// Per tile: vmcnt(8) -> barrier -> fence -> ds_read slot t -> stage(t+3)
//           -> setprio(1) 32 MFMA setprio(0).
// stage(t+3) writes slot (t-1)&3; ordering proof: issuing wave is past
// barrier t, and any wave's arrival at barrier t requires its tile t-1 MFMAs
// (lgkmcnt-drained ds_reads of slot (t-1)&3) to be complete.
// vmcnt: outstanding at wait = tiles {t,t+1,t+2} = 12 loads -> wait 8 drains
// tile t. Tail 8/4/0. Requires K mult of 32, NT >= 4, M,N mult of 256.
// ===========================================================================
template <int AMODE, int EPI>
__device__ __forceinline__ void gemm256_body(
    int bm, int bn, int M, int K,
    const __hip_bfloat16* __restrict__ A, int lda,
    const __hip_bfloat16* __restrict__ A2,
    const __hip_bfloat16* __restrict__ W,
    const float* __restrict__ bias,
    void* __restrict__ Cv, int ldc,
    const __hip_bfloat16* __restrict__ P,
    float* __restrict__ C32, int ldc32,
    short* As, short* Bs)   // 32768 shorts each: 4 slots x [256 rows][32 k]
{
    const int tid  = threadIdx.x;
    const int wave = tid >> 6;
    const int lane = tid & 63;
    const int wm = (wave >> 2) * 128;      // 2 row-wave groups
    const int wn = (wave & 3) * 64;        // 4 col-wave groups
    const int l16 = lane & 15, q4 = lane >> 4;

    // ---- staging maps (identical swizzle to verified round-5 kernel) ----
    const short* gA[2]; const short* gA2p[2]; const short* gB[2];
    int dOf[2];
#pragma unroll
    for (int r = 0; r < 2; ++r) {
        const int s   = r * 512 + tid;
        const int row = s >> 2;
        const int pc  = s & 3;
        const int j   = (pc - (row >> 1)) & 3;
        const int ga  = min(bm + row, M - 1);
        if (AMODE == AM_CONCAT) {
            gA[r]   = (const short*)A  + (size_t)ga * 1024 + j * 8;
            gA2p[r] = (const short*)A2 + (size_t)ga * 256  + j * 8;
        } else {
            gA[r]   = (const short*)A + (size_t)ga * lda + j * 8;
            gA2p[r] = nullptr;
        }
        gB[r]  = (const short*)W + (size_t)(bn + row) * K + j * 8;
        dOf[r] = (r * 512 + wave * 64) * 8;   // wave-uniform LDS base (shorts)
    }

    // ---- fragment read offsets within a slot ----
    int aof[8], bof[4];
#pragma unroll
    for (int m = 0; m < 8; ++m) {
        const int ra = wm + m * 16 + l16;
        aof[m] = ra * 32 + (((q4 + (ra >> 1)) & 3) << 3);
    }
#pragma unroll
    for (int n = 0; n < 4; ++n) {
        const int rb = wn + n * 16 + l16;
        bof[n] = rb * 32 + (((q4 + (rb >> 1)) & 3) << 3);
    }

    f32x4 acc[8][4] = {};
    const int NT = K >> 5;

    auto stage = [&](int t) {
        const int k0 = t << 5;
        const int sb = (t & 3) << 13;       // slot base in shorts (8192/slot)
#pragma unroll
        for (int r = 0; r < 2; ++r) {
            const short* ap;
            if (AMODE == AM_CONCAT)
                ap = (k0 < 1024) ? gA[r] + k0 : gA2p[r] + (k0 - 1024);
            else
                ap = gA[r] + k0;
            gld16(ap, &As[sb + dOf[r]]);
        }
#pragma unroll
        for (int r = 0; r < 2; ++r) gld16(gB[r] + k0, &Bs[sb + dOf[r]]);
    };

    // prologue: 3 tiles in flight (12 loads)
    stage(0); stage(1); stage(2);

#define STEP256(t_, DOISS_, VMS_) do {                                        \
        asm volatile("s_waitcnt vmcnt(" VMS_ ")" ::: "memory");               \
        __builtin_amdgcn_s_barrier();                                         \
        asm volatile("" ::: "memory"); /* keep stage below the barrier */     \
        const int cur_ = ((t_) & 3) << 13;                                    \
        s16x8 af_[8], bf_[4];                                                 \
        _Pragma("unroll")                                                     \
        for (int m = 0; m < 8; ++m) af_[m] = *(const s16x8*)&As[cur_ + aof[m]]; \
        _Pragma("unroll")                                                     \
        for (int n = 0; n < 4; ++n) bf_[n] = *(const s16x8*)&Bs[cur_ + bof[n]]; \
        if (DOISS_) stage((t_) + 3);                                          \
        __builtin_amdgcn_s_setprio(1);                                        \
        _Pragma("unroll")                                                     \
        for (int m = 0; m < 8; ++m)                                           \
            _Pragma("unroll")                                                 \
            for (int n = 0; n < 4; ++n)                                       \
                acc[m][n] = __builtin_amdgcn_mfma_f32_16x16x32_bf16(          \
                    af_[m], bf_[n], acc[m][n], 0, 0, 0);                      \
        __builtin_amdgcn_s_setprio(0);                                        \
    } while (0)

    for (int t = 0; t < NT - 3; ++t) STEP256(t, 1, "8");
    STEP256(NT - 3, 0, "8");
    STEP256(NT - 2, 0, "4");
    STEP256(NT - 1, 0, "0");
#undef STEP256

    // ---- epilogue (verified): C/D col=lane&15, row=q4*4+reg ----
    const int crow0 = bm + wm + q4 * 4;
    const int ccol0 = bn + wn + l16;
#pragma unroll
    for (int m8 = 0; m8 < 8; ++m8) {
#pragma unroll
        for (int r = 0; r < 4; ++r) {
            const int row = crow0 + m8 * 16 + r;
            if (row >= M) continue;
#pragma unroll
            for (int n4 = 0; n4 < 4; ++n4) {
                const int col = ccol0 + n4 * 16;
                float v = acc[m8][n4][r] + bias[col];
                if (EPI == EP_NONE) {
                    ((float*)Cv)[(size_t)row * ldc + col] = v;
                } else if (EPI == EP_SELU32) {
                    ((float*)Cv)[(size_t)row * ldc + col] = selu_f(v);
                } else if (EPI == EP_BRANCH) {
                    const int c = col >> 10, jj = col & 1023;
                    ((__hip_bfloat16*)Cv)[(size_t)(2 * row + c) * 1024 + jj] =
                        __float2bfloat16(selu_f(v));
                } else { // EP_RESID
                    const float pv = __bfloat162float(P[(size_t)(row >> 1) * 1024 + col]);
                    const float o = pv - selu_f(v);
                    ((__hip_bfloat16*)Cv)[(size_t)row * 1024 + col] = __float2bfloat16(o);
                    if (C32) C32[(size_t)row * ldc32 + col] = o;
                }
            }
        }
    }
}

template <int AMODE, int EPI>
__global__ __launch_bounds__(512) void mgemm256(
    int M, int N, int K,
    const __hip_bfloat16* __restrict__ A, int lda,
    const __hip_bfloat16* __restrict__ A2,
    const __hip_bfloat16* __restrict__ W,
    const float* __restrict__ bias,
    void* __restrict__ Cv, int ldc,
    const __hip_bfloat16* __restrict__ P,
    float* __restrict__ C32, int ldc32)
{
    __shared__ short As[32768];   // 64 KiB
    __shared__ short Bs[32768];   // 64 KiB
    int bxi = blockIdx.x, byi = blockIdx.y;
    {
        const int ncol = gridDim.x, nrow = gridDim.y;
        if ((nrow & 7) == 0) {
            const int lin = byi * ncol + bxi;
            const int xcd = lin & 7;
            const int t = lin >> 3;
            const int rows_per = nrow >> 3;
            bxi = t % ncol;
            byi = xcd * rows_per + t / ncol;
        }
    }
    gemm256_body<AMODE, EPI>(byi * 256, bxi * 256, M, K, A, lda, A2, W, bias,
                             Cv, ldc, P, C32, ldc32, As, Bs);
}

// ---- elementwise helpers ----
__global__ void cvt4_k(const float* __restrict__ s0, __hip_bfloat16* __restrict__ d0, int n0,
                       const float* __restrict__ s1, __hip_bfloat16* __restrict__ d1, int n1,
                       const float* __restrict__ s2, __hip_bfloat16* __restrict__ d2, int n2,
                       const float* __restrict__ s3, __hip_bfloat16* __restrict__ d3, int n3)
{
    int i = blockIdx.x * 256 + threadIdx.x;
    if (i < n0) { d0[i] = __float2bfloat16(s0[i]); return; }
    i -= n0;
    if (i < n1) { d1[i] = __float2bfloat16(s1[i]); return; }
    i -= n1;
    if (i < n2) { d2[i] = __float2bfloat16(s2[i]); return; }
    i -= n2;
    if (i < n3) { d3[i] = __float2bfloat16(s3[i]); }
}

__global__ void selu_cvt_k(const float* __restrict__ in, __hip_bfloat16* __restrict__ out, int n)
{
    int i = blockIdx.x * 256 + threadIdx.x;
    if (i < n) out[i] = __float2bfloat16(selu_f(in[i]));
}

__global__ void mean_kernel(const float* __restrict__ T, __hip_bfloat16* __restrict__ xc)
{
    const int idx = blockIdx.x * 256 + threadIdx.x; // 64*1024
    const int b = idx >> 10, h = idx & 1023;
    const float* p = T + (size_t)b * 32 * 1024 + h;
    float s = 0.f;
#pragma unroll
    for (int si = 0; si < 32; ++si) s += p[si * 1024];
    xc[idx] = __float2bfloat16(s * (1.f / 32.f));
}

__global__ __launch_bounds__(256) void gateshb_kernel(
    const float* __restrict__ gi,
    const float* __restrict__ gh,
    const float* __restrict__ b_hh,
    const __hip_bfloat16* __restrict__ hold,
    __hip_bfloat16* __restrict__ hnew,
    const __hip_bfloat16* __restrict__ xc,
    const float* __restrict__ W_hb,
    const float* __restrict__ b_hb,
    const float* __restrict__ depth_old,
    float* __restrict__ depth_out, int dstride,
    int first)
{
    const int m = blockIdx.x;
    const int j = threadIdx.x;
    __shared__ float red[4];

    const float* gim = gi + (size_t)m * 768;
    const float ir = gim[j], iz = gim[256 + j], in_ = gim[512 + j];
    float hr, hz, hn, h0;
    if (first) {
        hr = b_hh[j]; hz = b_hh[256 + j]; hn = b_hh[512 + j]; h0 = 0.f;
    } else {
        const float* ghm = gh + (size_t)(m >> 1) * 768;
        hr = ghm[j]; hz = ghm[256 + j]; hn = ghm[512 + j];
        h0 = __bfloat162float(hold[(size_t)(m >> 1) * 256 + j]);
    }
    const float r = sigmoid_f(ir + hr);
    const float z = sigmoid_f(iz + hz);
    const float n = tanhf(in_ + r * hn);
    const float hv = (1.f - z) * n + z * h0;
    hnew[(size_t)m * 256 + j] = __float2bfloat16(hv);

    const __hip_bfloat16* xr = xc + (size_t)m * 1024;
    float s = hv * W_hb[1024 + j];
#pragma unroll
    for (int kk = 0; kk < 4; ++kk) {
        const int k = j + kk * 256;
        s += __bfloat162float(xr[k]) * W_hb[k];
    }
#pragma unroll
    for (int off = 32; off; off >>= 1) s += __shfl_down(s, off);
    if ((j & 63) == 0) red[j >> 6] = s;
    __syncthreads();
    if (j == 0) {
        const float tot = red[0] + red[1] + red[2] + red[3];
        const float hb = sigmoid_f(tot + b_hb[0]);
        const float d0 = first ? 0.f : depth_old[m >> 1];
        depth_out[(size_t)m * dstride] = d0 + hb;
    }
}

extern "C" void kernel_launch(void* const* d_in, const int* in_sizes, int n_in,
                              void* d_out, int out_size, void* d_ws, size_t ws_size,
                              hipStream_t stream)
{
    const float* x        = (const float*)d_in[0];
    const float* W_hidden = (const float*)d_in[1];
    const float* b_hidden = (const float*)d_in[2];
    const float* W_hb     = (const float*)d_in[3];
    const float* b_hb     = (const float*)d_in[4];
    const float* W_branch = (const float*)d_in[5];
    const float* b_branch = (const float*)d_in[6];
    const float* W_ih     = (const float*)d_in[7];
    const float* W_hh     = (const float*)d_in[8];
    const float* b_ih     = (const float*)d_in[9];
    const float* b_hh     = (const float*)d_in[10];

    char* ws = (char*)d_ws;
    size_t off = 0;
    auto alloc = [&](size_t bytes) {
        void* p = ws + off;
        off += (bytes + 255) & ~(size_t)255;
        return p;
    };
    __hip_bfloat16* Whb  = (__hip_bfloat16*)alloc(1024 * 1024 * 2);
    __hip_bfloat16* Wbb  = (__hip_bfloat16*)alloc(2048 * 1280 * 2);
    __hip_bfloat16* Wib  = (__hip_bfloat16*)alloc(768 * 1024 * 2);
    __hip_bfloat16* Whh  = (__hip_bfloat16*)alloc(768 * 256 * 2);
    __hip_bfloat16* Xs   = (__hip_bfloat16*)alloc((size_t)2048 * 1024 * 2);
    float*          GI   = (float*)alloc((size_t)32768 * 768 * 4);
    __hip_bfloat16* U    = (__hip_bfloat16*)alloc((size_t)32768 * 1024 * 2);
    __hip_bfloat16* XC0  = (__hip_bfloat16*)alloc((size_t)32768 * 1024 * 2);
    __hip_bfloat16* XC1  = (__hip_bfloat16*)alloc((size_t)32768 * 1024 * 2);
    __hip_bfloat16* HC0  = (__hip_bfloat16*)alloc((size_t)32768 * 256 * 2);
    __hip_bfloat16* HC1  = (__hip_bfloat16*)alloc((size_t)32768 * 256 * 2);
    float*          D0   = (float*)alloc(32768 * 4);
    float*          D1   = (float*)alloc(32768 * 4);
    float*          GH   = (float*)U;   // time-shared with U

    float* out = (float*)d_out; // [32768, 1025]

    {
        const int n0 = 1024 * 1024, n1 = 2048 * 1280, n2 = 768 * 1024, n3 = 768 * 256;
        cvt4_k<<<(n0 + n1 + n2 + n3 + 255) / 256, 256, 0, stream>>>(
            W_hidden, Whb, n0, W_branch, Wbb, n1, W_ih, Wib, n2, W_hh, Whh, n3);
    }
    selu_cvt_k<<<(2048 * 1024 + 255) / 256, 256, 0, stream>>>(x, Xs, 2048 * 1024);

    mgemm<AM_PLAIN, EP_SELU32><<<dim3(1024 / 128, 2048 / 128), 256, 0, stream>>>(
        2048, 1024, 1024, Xs, 1024, nullptr, Whb, b_hidden, GI, 1024, nullptr, nullptr, 0);
    mean_kernel<<<(64 * 1024) / 256, 256, 0, stream>>>(GI, XC0);

    __hip_bfloat16* xc_cur = XC0; __hip_bfloat16* xc_next = XC1;
    __hip_bfloat16* hc_prev = nullptr; __hip_bfloat16* hc_new = HC0;
    float* d_prev = nullptr; float* d_next = D0;

    for (int d = 0; d < 9; ++d) {
        const int M = 64 << d; // 64 .. 16384
        GPair g;
        g.M0 = M;     g.K0 = 1024; g.A0 = xc_cur;  g.lda0 = 1024;
        g.W0 = Wib;   g.b0 = b_ih; g.C0 = GI;      g.ldc0 = 768;
        g.M1 = M / 2; g.K1 = 256;  g.A1 = hc_prev; g.lda1 = 256;
        g.W1 = Whh;   g.b1 = b_hh; g.C1 = GH;      g.ldc1 = 768;
        mgemm_pair<<<dim3(768 / 128, (M + 127) / 128, d > 0 ? 2 : 1), 256, 0, stream>>>(g);

        gateshb_kernel<<<M, 256, 0, stream>>>(
            GI, (const float*)GH, b_hh, hc_prev, hc_new,
            xc_cur, W_hb, b_hb, d_prev, d_next, 1, d == 0 ? 1 : 0);

        if (d >= 7) {
            // grids >= 256 blocks: pipelined 256^2 path
            mgemm256<AM_CONCAT, EP_BRANCH><<<dim3(2048 / 256, M / 256), 512, 0, stream>>>(
                M, 2048, 1280, xc_cur, 1024, hc_new, Wbb, b_branch, U, 1024,
                nullptr, nullptr, 0);
            mgemm256<AM_PLAIN, EP_RESID><<<dim3(1024 / 256, (2 * M) / 256), 512, 0, stream>>>(
                2 * M, 1024, 1024, U, 1024, nullptr, Whb, b_hidden, xc_next, 1024,
                xc_cur, d == 8 ? out : nullptr, 1025);
        } else {
            mgemm<AM_CONCAT, EP_BRANCH><<<dim3(2048 / 128, (M + 127) / 128), 256, 0, stream>>>(
                M, 2048, 1280, xc_cur, 1024, hc_new, Wbb, b_branch, U, 1024,
                nullptr, nullptr, 0);
            mgemm<AM_PLAIN, EP_RESID><<<dim3(1024 / 128, (2 * M) / 128), 256, 0, stream>>>(
                2 * M, 1024, 1024, U, 1024, nullptr, Whb, b_hidden, xc_next, 1024,
                xc_cur, d == 8 ? out : nullptr, 1025);
        }

        __hip_bfloat16* t = xc_cur; xc_cur = xc_next; xc_next = t;
        hc_prev = hc_new; hc_new = (hc_new == HC0) ? HC1 : HC0;
        d_prev = d_next;  d_next = (d_next == D0) ? D1 : D0;
    }

    // ---- final GRU + leaf depth, M = 32768 ----
    {
        const int M = 32768;
        // gi: 384-block 256^2 pipelined launch; gh small -> legacy path
        mgemm256<AM_PLAIN, EP_NONE><<<dim3(768 / 256, M / 256), 512, 0, stream>>>(
            M, 768, 1024, xc_cur, 1024, nullptr, Wib, b_ih, GI, 768,
            nullptr, nullptr, 0);
        mgemm<AM_PLAIN, EP_NONE><<<dim3(768 / 128, (M / 2) / 128), 256, 0, stream>>>(
            M / 2, 768, 256, hc_prev, 256, nullptr, Whh, b_hh, (void*)GH, 768,
            nullptr, nullptr, 0);
        gateshb_kernel<<<M, 256, 0, stream>>>(
            GI, (const float*)GH, b_hh, hc_prev, hc_new,
            xc_cur, W_hb, b_hb, d_prev, out + 1024, 1025, 0);
    }
}